// Round 3
// baseline (86.143 us; speedup 1.0000x reference)
//
#include <hip/hip_runtime.h>

// AdaptiveHyperNN, fully collapsed (all layers affine until sigmoid):
//   logit[b,u,v] = A[b,u] + B[b,v] + C[b]
//   wa/wb = W3[:D]/W3[D:] @ w4t            (w4t = W4[:D,0])
//   u2{a,b} = W2[D:]@w{a,b}, w2t{a,b} = W2[:D]@w{a,b}
//   va/vb = w2t{a,b} + W1[D:]@u2{a,b}, qsum = W1[:D]@(u2a+u2b)
//   A = feat@va, B = feat@vb
//   C[b] = (1/128)*Sum_u feat[b,u]·qsum + b1·(u2a+u2b) + b2·(wa+wb)
//          + b3·w4t + Xs[b]·W4[D:,0] + b4
// Single persistent kernel; stages ordered by device-scope counter syncs.
// feat never hits global memory: the gathering wave keeps its row in VGPRs
// and later computes the three dots itself.

#define SCOPE __HIP_MEMORY_SCOPE_AGENT

__device__ __forceinline__ float wred(float v) {
#pragma unroll
  for (int o = 32; o > 0; o >>= 1) v += __shfl_xor(v, o, 64);
  return v;
}
__device__ __forceinline__ float dot4(float4 a, float4 b) {
  return a.x * b.x + a.y * b.y + a.z * b.z + a.w * b.w;
}
__device__ __forceinline__ void blk_signal(int* c) {
  __syncthreads();  // all block stores done (wg release) ...
  if (threadIdx.x == 0)  // ... then one agent-scope release add
    __hip_atomic_fetch_add(c, 1, __ATOMIC_RELEASE, SCOPE);
}
__device__ __forceinline__ void blk_wait(int* c, int target) {
  if (threadIdx.x == 0) {
    while (__hip_atomic_load(c, __ATOMIC_ACQUIRE, SCOPE) < target)
      __builtin_amdgcn_s_sleep(4);
  }
  __syncthreads();  // propagate acquire to the block
}

// ws float layout
#define OFF_WA    0
#define OFF_WB    256
#define OFF_U2A   512
#define OFF_U2B   768
#define OFF_W2TA  1024
#define OFF_W2TB  1280
#define OFF_VA    1536
#define OFF_VB    1792
#define OFF_QSUM  2048
#define OFF_CALL  2304   // 8 floats: sAll + c0[g]
#define OFF_BG    2560   // 1024: B[g][u]
#define OFF_SC    3584   // 1024: feat[g][u]·qsum
#define OFF_SYNC  4608   // ints: cnt1,cnt2,cntF,pad...,gcnt[8]  (64 B, memset)

__global__ __launch_bounds__(256) void k_fused(
    const float* __restrict__ Xs, const float* __restrict__ api,
    const float* __restrict__ W1, const float* __restrict__ b1,
    const float* __restrict__ W2, const float* __restrict__ b2,
    const float* __restrict__ W3, const float* __restrict__ b3,
    const float* __restrict__ W4, const float* __restrict__ b4,
    const int* __restrict__ invoked, float* __restrict__ out,
    float* __restrict__ ws) {
  const int blk = blockIdx.x, tid = threadIdx.x;
  const int lane = tid & 63, wv = tid >> 6;

  float* wa   = ws + OFF_WA;   float* wb   = ws + OFF_WB;
  float* u2a  = ws + OFF_U2A;  float* u2b  = ws + OFF_U2B;
  float* w2ta = ws + OFF_W2TA; float* w2tb = ws + OFF_W2TB;
  float* va   = ws + OFF_VA;   float* vb   = ws + OFF_VB;
  float* qsum = ws + OFF_QSUM; float* cAll = ws + OFF_CALL;
  float* Bg   = ws + OFF_BG;   float* scar = ws + OFF_SC;
  int* sync   = (int*)(ws + OFF_SYNC);
  int* cnt1 = sync + 0; int* cnt2 = sync + 1; int* cntF = sync + 2;
  int* gcnt = sync + 8;

  __shared__ float Bsh[128];
  __shared__ float c0sh[8];
  __shared__ float sP2sh, sAllSh, CbSh;

  if (blk < 128) {
    // ---- weight chain: 4 waves = 4 rows per stage ----
    const int r = blk * 4 + wv;  // 0..511
    float4 w4a = ((const float4*)W4)[lane];
    {  // stage 1: W3 @ w4t
      float4 rv = ((const float4*)(W3 + r * 256))[lane];
      float s = wred(dot4(rv, w4a));
      if (lane == 0) { if (r < 256) wa[r] = s; else wb[r - 256] = s; }
    }
    blk_signal(cnt1);
    blk_wait(cnt1, 128);
    {  // stage 2: W2 @ {wa,wb}
      float4 a4 = ((const float4*)wa)[lane];
      float4 b4v = ((const float4*)wb)[lane];
      float4 rv = ((const float4*)(W2 + r * 256))[lane];
      float sa = wred(dot4(rv, a4));
      float sb = wred(dot4(rv, b4v));
      if (lane == 0) {
        if (r < 256) { w2ta[r] = sa; w2tb[r] = sb; }
        else         { u2a[r - 256] = sa; u2b[r - 256] = sb; }
      }
    }
    blk_signal(cnt2);
    blk_wait(cnt2, 128);
    {  // stage 3: W1 @ {u2a,u2b}
      float4 a4 = ((const float4*)u2a)[lane];
      float4 b4v = ((const float4*)u2b)[lane];
      float4 rv = ((const float4*)(W1 + r * 256))[lane];
      if (r < 256) {
        float s = wred(dot4(rv, a4) + dot4(rv, b4v));
        if (lane == 0) qsum[r] = s;
      } else {
        float sa = wred(dot4(rv, a4));
        float sb = wred(dot4(rv, b4v));
        if (lane == 0) { va[r - 256] = w2ta[r - 256] + sa;
                         vb[r - 256] = w2tb[r - 256] + sb; }
      }
    }
    blk_signal(cntF);
  } else if (blk == 128) {
    // ---- scalar constants ----
    float4 w4a = ((const float4*)W4)[lane];
    float4 w4b4 = ((const float4*)W4)[lane + 64];
    float sb3 = wred(dot4(((const float4*)b3)[lane], w4a));
    for (int bi = wv; bi < 8; bi += 4) {
      float xd = wred(dot4(((const float4*)(Xs + bi * 256))[lane], w4b4));
      if (lane == 0) c0sh[bi] = b4[0] + sb3 + xd;
    }
    blk_wait(cnt1, 128);
    if (wv == 0) {
      float4 a4 = ((const float4*)wa)[lane];
      float4 b4v = ((const float4*)wb)[lane];
      float4 s4 = make_float4(a4.x + b4v.x, a4.y + b4v.y,
                              a4.z + b4v.z, a4.w + b4v.w);
      float s = wred(dot4(((const float4*)b2)[lane], s4));
      if (lane == 0) sP2sh = s;
    }
    blk_wait(cnt2, 128);
    if (wv == 0) {
      float4 a4 = ((const float4*)u2a)[lane];
      float4 b4v = ((const float4*)u2b)[lane];
      float4 s4 = make_float4(a4.x + b4v.x, a4.y + b4v.y,
                              a4.z + b4v.z, a4.w + b4v.w);
      float s = wred(dot4(((const float4*)b1)[lane], s4));
      if (lane == 0) sAllSh = sP2sh + s;
    }
    __syncthreads();
    if (tid < 8) cAll[tid] = c0sh[tid] + sAllSh;
    blk_signal(cntF);
  } else {
    // ---- gather + final: wave's feat row lives in registers ----
    const int gid = blk - 129;       // 0..255
    const int row = gid * 4 + wv;    // 0..1023
    const int g = row >> 7, u = row & 127;
    int idx = invoked[row];          // wave-uniform
    float4 rv = ((const float4*)(api + (size_t)idx * 256))[lane];
    blk_wait(cntF, 129);             // gather HBM latency hides under chain
    float4 va4 = ((const float4*)va)[lane];
    float4 vb4 = ((const float4*)vb)[lane];
    float4 q4 = ((const float4*)qsum)[lane];
    float sa = wred(dot4(rv, va4));  // A[u] — stays wave-local
    float sb = wred(dot4(rv, vb4));
    float sc = wred(dot4(rv, q4));
    if (lane == 0) { Bg[row] = sb; scar[row] = sc; }
    blk_signal(&gcnt[g]);
    blk_wait(&gcnt[g], 32);          // 32 blocks per graph
    if (tid < 128) Bsh[tid] = Bg[(g << 7) + tid];
    if (wv == 0) {  // deterministic fixed-order Cb reduction
      float t = scar[(g << 7) + lane] + scar[(g << 7) + 64 + lane];
      t = wred(t);
      if (lane == 0) CbSh = t * (1.f / 128.f) + cAll[g];
    }
    __syncthreads();
    float Cb = CbSh;
    float2* ob = (float2*)(out + (g << 14) + (u << 7));
    float x0 = sa + Bsh[2 * lane] + Cb;
    float x1 = sa + Bsh[2 * lane + 1] + Cb;
    ob[lane] = make_float2(1.f / (1.f + __expf(-x0)),
                           1.f / (1.f + __expf(-x1)));
  }
}

extern "C" void kernel_launch(void* const* d_in, const int* in_sizes, int n_in,
                              void* d_out, int out_size, void* d_ws, size_t ws_size,
                              hipStream_t stream) {
  const float* Xs  = (const float*)d_in[0];
  const float* api = (const float*)d_in[1];
  const float* W1  = (const float*)d_in[2];
  const float* b1  = (const float*)d_in[3];
  const float* W2  = (const float*)d_in[4];
  const float* b2  = (const float*)d_in[5];
  const float* W3  = (const float*)d_in[6];
  const float* b3  = (const float*)d_in[7];
  const float* W4  = (const float*)d_in[8];
  const float* b4  = (const float*)d_in[9];
  const int* invoked = (const int*)d_in[10];
  float* out = (float*)d_out;
  float* ws = (float*)d_ws;

  // counters must be zero every call (ws is poisoned, never re-poisoned)
  hipMemsetAsync((char*)d_ws + OFF_SYNC * sizeof(float), 0, 64, stream);
  hipLaunchKernelGGL(k_fused, dim3(385), dim3(256), 0, stream,
                     Xs, api, W1, b1, W2, b2, W3, b3, W4, b4, invoked, out, ws);
}

// Round 4
// 60.961 us; speedup vs baseline: 1.4131x; 1.4131x over previous
//
#include <hip/hip_runtime.h>

// AdaptiveHyperNN, fully collapsed (all layers affine until the sigmoid):
//   logit[b,u,v] = feat_u·va + feat_v·vb + Cb
//   wa/wb = W3[:256]/W3[256:] @ w4t          (w4t = W4[:256,0])
//   w2t{a,b} = W2[:256]@w{a,b}, u2{a,b} = W2[256:]@w{a,b}
//   va/vb = w2t{a,b} + W1[256:]@u2{a,b}, qsum = W1[:256]@(u2a+u2b)
//   Cb = (1/128)·Σ_u feat_u·qsum + b1·(u2a+u2b) + b2·(wa+wb)
//        + b3·w4t + Xs[b]·W4[256:,0] + b4
// Round-3 lesson: device-scope counter barriers cost ~20-30 µs/round on
// MI355X (serialized agent-scope RMWs at the coherence point). So: ONE
// launch, ONE block per graph, the whole chain per-block with
// __syncthreads() only. Weights are small (1.5 MB/block); feat rows live
// in VGPRs from gather to final dots. No workspace, no memset.

__device__ __forceinline__ float wred(float v) {
#pragma unroll
  for (int o = 32; o > 0; o >>= 1) v += __shfl_xor(v, o, 64);
  return v;
}
__device__ __forceinline__ float dot4(float4 a, float4 b) {
  return a.x * b.x + a.y * b.y + a.z * b.z + a.w * b.w;
}

__global__ __launch_bounds__(1024) void k_all(
    const float* __restrict__ Xs, const float* __restrict__ api,
    const float* __restrict__ W1, const float* __restrict__ b1,
    const float* __restrict__ W2, const float* __restrict__ b2,
    const float* __restrict__ W3, const float* __restrict__ b3,
    const float* __restrict__ W4, const float* __restrict__ b4,
    const int* __restrict__ invoked, float* __restrict__ out) {
  const int g = blockIdx.x;           // graph 0..7
  const int tid = threadIdx.x;
  const int lane = tid & 63;
  const int wv = tid >> 6;            // wave 0..15

  __shared__ alignas(16) float wa[256], wb[256];
  __shared__ alignas(16) float u2a[256], u2b[256], w2ta[256], w2tb[256];
  __shared__ alignas(16) float va[256], vb[256], qs[256];
  __shared__ alignas(16) float Ash[128], Bsh[128], scsh[128];
  __shared__ float sP2sh, cAllSh, CbSh;

  // ---- phase 1: gather this graph's 128 feat rows into registers ----
  // 8 rows per wave, one float4 per lane per row. Loads stay in flight
  // while the weight chain runs; regs are consumed only in phase 5.
  float4 f[8];
  const int ub = wv * 8;
#pragma unroll
  for (int i = 0; i < 8; ++i) {
    int idx = invoked[(g << 7) + ub + i];   // wave-uniform
    f[i] = ((const float4*)(api + (size_t)idx * 256))[lane];
  }

  // ---- phase 2: wa/wb = W3 @ w4t (32 rows per wave) ----
  const float4 w4a = ((const float4*)W4)[lane];
  const int r0 = wv * 32;
  if (wv < 8) {
#pragma unroll 4
    for (int i = 0; i < 32; ++i) {
      int r = r0 + i;
      float s = wred(dot4(((const float4*)(W3 + (size_t)r * 256))[lane], w4a));
      if (lane == 0) wa[r] = s;
    }
    if (wv == 0) {  // c0 part: b3·w4t + Xs[g]·w4b + b4 (chain-independent)
      float4 w4b4 = ((const float4*)W4)[lane + 64];
      float part = dot4(((const float4*)b3)[lane], w4a) +
                   dot4(((const float4*)(Xs + g * 256))[lane], w4b4);
      float s = wred(part);
      if (lane == 0) cAllSh = b4[0] + s;
    }
  } else {
#pragma unroll 4
    for (int i = 0; i < 32; ++i) {
      int r = r0 + i;
      float s = wred(dot4(((const float4*)(W3 + (size_t)r * 256))[lane], w4a));
      if (lane == 0) wb[r - 256] = s;
    }
  }
  __syncthreads();

  // ---- phase 3: W2 stage ----
  {
    float4 a4 = ((const float4*)wa)[lane];
    float4 b4v = ((const float4*)wb)[lane];
    if (wv < 8) {
#pragma unroll 4
      for (int i = 0; i < 32; ++i) {
        int r = r0 + i;
        float4 rv = ((const float4*)(W2 + (size_t)r * 256))[lane];
        float sa = wred(dot4(rv, a4));
        float sb = wred(dot4(rv, b4v));
        if (lane == 0) { w2ta[r] = sa; w2tb[r] = sb; }
      }
      if (wv == 0) {  // sP2 = b2·(wa+wb)
        float4 s4 = make_float4(a4.x + b4v.x, a4.y + b4v.y,
                                a4.z + b4v.z, a4.w + b4v.w);
        float s = wred(dot4(((const float4*)b2)[lane], s4));
        if (lane == 0) sP2sh = s;
      }
    } else {
#pragma unroll 4
      for (int i = 0; i < 32; ++i) {
        int r = r0 + i;
        float4 rv = ((const float4*)(W2 + (size_t)r * 256))[lane];
        float sa = wred(dot4(rv, a4));
        float sb = wred(dot4(rv, b4v));
        if (lane == 0) { u2a[r - 256] = sa; u2b[r - 256] = sb; }
      }
    }
  }
  __syncthreads();

  // ---- phase 4: W1 stage ----
  {
    float4 a4 = ((const float4*)u2a)[lane];
    float4 b4v = ((const float4*)u2b)[lane];
    float4 s4 = make_float4(a4.x + b4v.x, a4.y + b4v.y,
                            a4.z + b4v.z, a4.w + b4v.w);
    if (wv < 8) {  // qsum rows
#pragma unroll 4
      for (int i = 0; i < 32; ++i) {
        int r = r0 + i;
        float s = wred(dot4(((const float4*)(W1 + (size_t)r * 256))[lane], s4));
        if (lane == 0) qs[r] = s;
      }
      if (wv == 0) {  // fold b1·(u2a+u2b) + sP2 into cAll
        float s = wred(dot4(((const float4*)b1)[lane], s4));
        if (lane == 0) cAllSh = cAllSh + sP2sh + s;
      }
    } else {       // va/vb rows
#pragma unroll 4
      for (int i = 0; i < 32; ++i) {
        int r = r0 + i;
        float4 rv = ((const float4*)(W1 + (size_t)r * 256))[lane];
        float sa = wred(dot4(rv, a4));
        float sb = wred(dot4(rv, b4v));
        if (lane == 0) { va[r - 256] = w2ta[r - 256] + sa;
                         vb[r - 256] = w2tb[r - 256] + sb; }
      }
    }
  }
  __syncthreads();

  // ---- phase 5: per-u dots from registers ----
  {
    float4 va4 = ((const float4*)va)[lane];
    float4 vb4 = ((const float4*)vb)[lane];
    float4 q4  = ((const float4*)qs)[lane];
#pragma unroll
    for (int i = 0; i < 8; ++i) {
      float sa = wred(dot4(f[i], va4));
      float sb = wred(dot4(f[i], vb4));
      float sc = wred(dot4(f[i], q4));
      if (lane == 0) { Ash[ub + i] = sa; Bsh[ub + i] = sb; scsh[ub + i] = sc; }
    }
  }
  __syncthreads();

  // ---- phase 6: Cb (deterministic fixed-order reduction) ----
  if (wv == 0) {
    float t = scsh[lane] + scsh[lane + 64];
    t = wred(t);
    if (lane == 0) CbSh = t * (1.f / 128.f) + cAllSh;
  }
  __syncthreads();

  // ---- phase 7: 16K sigmoids, float4 stores ----
  const float Cb = CbSh;
  float4* ob = (float4*)(out + (g << 14));
#pragma unroll
  for (int j = 0; j < 4; ++j) {
    int e4 = tid + (j << 10);          // float4 index 0..4095
    float a = Ash[e4 >> 5] + Cb;       // u = (e4*4)>>7 = e4>>5
    float4 bv = ((const float4*)Bsh)[e4 & 31];
    float4 r;
    r.x = 1.f / (1.f + __expf(-(a + bv.x)));
    r.y = 1.f / (1.f + __expf(-(a + bv.y)));
    r.z = 1.f / (1.f + __expf(-(a + bv.z)));
    r.w = 1.f / (1.f + __expf(-(a + bv.w)));
    ob[e4] = r;
  }
}

extern "C" void kernel_launch(void* const* d_in, const int* in_sizes, int n_in,
                              void* d_out, int out_size, void* d_ws, size_t ws_size,
                              hipStream_t stream) {
  const float* Xs  = (const float*)d_in[0];
  const float* api = (const float*)d_in[1];
  const float* W1  = (const float*)d_in[2];
  const float* b1  = (const float*)d_in[3];
  const float* W2  = (const float*)d_in[4];
  const float* b2  = (const float*)d_in[5];
  const float* W3  = (const float*)d_in[6];
  const float* b3  = (const float*)d_in[7];
  const float* W4  = (const float*)d_in[8];
  const float* b4  = (const float*)d_in[9];
  const int* invoked = (const int*)d_in[10];
  float* out = (float*)d_out;

  hipLaunchKernelGGL(k_all, dim3(8), dim3(1024), 0, stream,
                     Xs, api, W1, b1, W2, b2, W3, b3, W4, b4, invoked, out);
}

// Round 5
// 29.204 us; speedup vs baseline: 2.9497x; 2.0874x over previous
//
#include <hip/hip_runtime.h>

// AdaptiveHyperNN, collapsed + matmul-flattened to dependency depth 2:
//   logit[b,u,v] = feat_u·va + feat_v·vb + Cb, sigmoid at the end.
//   L1 (independent):
//     PM[0:256]   = W1top @ W2bot                      (qsum matrix)
//     PM[256:512] = W2top + W1bot @ W2bot              (va/vb matrix)
//     PM[512]     = W2bot^T @ b1 + b2                  (sAll vector)
//     wa/wb = W3[:256]/W3[256:] @ W4[:256,0]
//     c0[g] = b3·w4t + Xs[g]·W4[256:,0] + b4
//   L2: va = PM[256+r]·wa, vb = PM[256+r]·wb, qsum[r] = PM[r]·(wa+wb)
//       cAll[g] = c0[g] + PM[512]·(wa+wb)
//   L3 (per graph): gather feat to regs, A[u]=feat·va, B[v]=feat·vb,
//       Cb = (1/128)·Σ feat·qsum + cAll[g], out = sigmoid(A+B+Cb).
// R3 lesson: no cross-block atomics (20-30 µs/round). R4 lesson: never
// stream the weight set from <16 CUs (24 GB/s/CU). Hence 3 wide launches.

__device__ __forceinline__ float wred(float v) {
#pragma unroll
  for (int o = 32; o > 0; o >>= 1) v += __shfl_xor(v, o, 64);
  return v;
}
__device__ __forceinline__ float dot4(float4 a, float4 b) {
  return a.x * b.x + a.y * b.y + a.z * b.z + a.w * b.w;
}

// ws float offsets
#define OFF_PM   0        // 513*256 = 131328
#define OFF_WA   131328   // 256
#define OFF_WB   131584   // 256
#define OFF_VA   131840   // 256
#define OFF_VB   132096   // 256
#define OFF_QS   132352   // 256
#define OFF_C0   132608   // 8
#define OFF_CALL 132616   // 8   (total 530 KB)

// L1: blocks 0..127: PM GEMM, 4 rows/block (thread = (rowgrp, col4));
//     blocks 128..255: wa/wb wave-per-row dots; block 256: PM[512] + c0.
__global__ __launch_bounds__(256) void k1(
    const float* __restrict__ Xs, const float* __restrict__ W1,
    const float* __restrict__ b1, const float* __restrict__ W2,
    const float* __restrict__ b2, const float* __restrict__ W3,
    const float* __restrict__ b3, const float* __restrict__ W4,
    const float* __restrict__ b4, float* __restrict__ ws) {
  const int blk = blockIdx.x, tid = threadIdx.x;
  float* PM = ws + OFF_PM;
  const float* W2bot = W2 + 256 * 256;

  if (blk < 128) {
    // ---- PM rows r0..r0+3: PM[r] = W1[r] @ W2bot (+ W2top[r-256]) ----
    const int r0 = blk * 4;
    const int c4 = tid & 63, rg = tid >> 6;   // rg uniform per wave
    __shared__ float w1s[4][256];
#pragma unroll
    for (int i = 0; i < 4; ++i) w1s[i][tid] = W1[(size_t)(r0 + i) * 256 + tid];
    __syncthreads();
    const float4* w2b4 = (const float4*)W2bot;
    float4 acc = make_float4(0.f, 0.f, 0.f, 0.f);
#pragma unroll 8
    for (int k = 0; k < 256; ++k) {
      float4 wv = w2b4[k * 64 + c4];
      float w1v = w1s[rg][k];                  // wave-uniform LDS broadcast
      acc.x += w1v * wv.x; acc.y += w1v * wv.y;
      acc.z += w1v * wv.z; acc.w += w1v * wv.w;
    }
    const int r = r0 + rg;
    if (r >= 256) {                            // block-uniform branch
      float4 t = ((const float4*)(W2 + (size_t)(r - 256) * 256))[c4];
      acc.x += t.x; acc.y += t.y; acc.z += t.z; acc.w += t.w;
    }
    ((float4*)(PM + (size_t)r * 256))[c4] = acc;
  } else if (blk < 256) {
    // ---- wa/wb = W3 @ w4t, wave per row ----
    const int lane = tid & 63, wv = tid >> 6;
    const int t = (blk - 128) * 4 + wv;        // 0..511
    float4 w4a = ((const float4*)W4)[lane];
    float4 rv = ((const float4*)(W3 + (size_t)t * 256))[lane];
    float s = wred(dot4(rv, w4a));
    if (lane == 0) {
      if (t < 256) ws[OFF_WA + t] = s; else ws[OFF_WB + t - 256] = s;
    }
  } else {
    // ---- c0 scalars + PM[512] = W2bot^T @ b1 + b2 ----
    const int lane = tid & 63, wv = tid >> 6;
    float4 w4a = ((const float4*)W4)[lane];
    float4 w4b4 = ((const float4*)W4)[lane + 64];
    float sb3 = wred(dot4(((const float4*)b3)[lane], w4a));
    for (int bi = wv; bi < 8; bi += 4) {
      float xd = wred(dot4(((const float4*)(Xs + (size_t)bi * 256))[lane], w4b4));
      if (lane == 0) ws[OFF_C0 + bi] = b4[0] + sb3 + xd;
    }
    const int c4 = tid & 63, rg = tid >> 6;    // k-split over rg
    const float4* w2b4 = (const float4*)W2bot;
    float4 acc = make_float4(0.f, 0.f, 0.f, 0.f);
#pragma unroll 8
    for (int i = 0; i < 64; ++i) {
      int k = rg * 64 + i;
      float4 wv = w2b4[k * 64 + c4];
      float bv = b1[k];
      acc.x += bv * wv.x; acc.y += bv * wv.y;
      acc.z += bv * wv.z; acc.w += bv * wv.w;
    }
    __shared__ float4 part[4][64];
    part[rg][c4] = acc;
    __syncthreads();
    if (tid < 64) {
      float4 s = part[0][tid], t1 = part[1][tid], t2 = part[2][tid], t3 = part[3][tid];
      float4 bb = ((const float4*)b2)[tid];
      s.x += t1.x + t2.x + t3.x + bb.x; s.y += t1.y + t2.y + t3.y + bb.y;
      s.z += t1.z + t2.z + t3.z + bb.z; s.w += t1.w + t2.w + t3.w + bb.w;
      ((float4*)(PM + (size_t)512 * 256))[tid] = s;
    }
  }
}

// L2: blocks 0..127: wave-row dots against PM; block 128: cAll.
__global__ __launch_bounds__(256) void k2(
    float* __restrict__ ws) {
  const int blk = blockIdx.x, tid = threadIdx.x;
  const int lane = tid & 63, wv = tid >> 6;
  const float* PM = ws + OFF_PM;
  float4 wa4 = ((const float4*)(ws + OFF_WA))[lane];
  float4 wb4 = ((const float4*)(ws + OFF_WB))[lane];
  if (blk < 128) {
    const int t = blk * 4 + wv;                // 0..511, wave-uniform branch
    if (t < 256) {
      float4 rv = ((const float4*)(PM + (size_t)(256 + t) * 256))[lane];
      float sa = wred(dot4(rv, wa4));
      float sb = wred(dot4(rv, wb4));
      if (lane == 0) { ws[OFF_VA + t] = sa; ws[OFF_VB + t] = sb; }
    } else {
      float4 rv = ((const float4*)(PM + (size_t)(t - 256) * 256))[lane];
      float4 s4 = make_float4(wa4.x + wb4.x, wa4.y + wb4.y,
                              wa4.z + wb4.z, wa4.w + wb4.w);
      float s = wred(dot4(rv, s4));
      if (lane == 0) ws[OFF_QS + t - 256] = s;
    }
  } else {
    __shared__ float sAllSh;
    if (wv == 0) {
      float4 rv = ((const float4*)(PM + (size_t)512 * 256))[lane];
      float4 s4 = make_float4(wa4.x + wb4.x, wa4.y + wb4.y,
                              wa4.z + wb4.z, wa4.w + wb4.w);
      float s = wred(dot4(rv, s4));
      if (lane == 0) sAllSh = s;
    }
    __syncthreads();
    if (tid < 8) ws[OFF_CALL + tid] = ws[OFF_C0 + tid] + sAllSh;
  }
}

// L3: one block (1024 thr) per graph: gather->regs, 3 dots/row, sigmoid.
__global__ __launch_bounds__(1024) void k3(
    const float* __restrict__ api, const int* __restrict__ invoked,
    const float* __restrict__ ws, float* __restrict__ out) {
  const int g = blockIdx.x, tid = threadIdx.x;
  const int lane = tid & 63, wv = tid >> 6;   // wv 0..15
  __shared__ float Ash[128], Bsh[128], scsh[128];
  __shared__ float CbSh;

  // gather 8 rows/wave into regs (8-deep MLP, hides HBM latency)
  float4 f[8];
  const int ub = wv * 8;
  int idx[8];
#pragma unroll
  for (int i = 0; i < 8; ++i) idx[i] = invoked[(g << 7) + ub + i];
#pragma unroll
  for (int i = 0; i < 8; ++i)
    f[i] = ((const float4*)(api + (size_t)idx[i] * 256))[lane];

  float4 va4 = ((const float4*)(ws + OFF_VA))[lane];
  float4 vb4 = ((const float4*)(ws + OFF_VB))[lane];
  float4 q4  = ((const float4*)(ws + OFF_QS))[lane];
#pragma unroll
  for (int i = 0; i < 8; ++i) {
    float sa = wred(dot4(f[i], va4));
    float sb = wred(dot4(f[i], vb4));
    float sc = wred(dot4(f[i], q4));
    if (lane == 0) { Ash[ub + i] = sa; Bsh[ub + i] = sb; scsh[ub + i] = sc; }
  }
  __syncthreads();
  if (wv == 0) {  // deterministic fixed-order Cb reduction
    float t = scsh[lane] + scsh[lane + 64];
    t = wred(t);
    if (lane == 0) CbSh = t * (1.f / 128.f) + ws[OFF_CALL + g];
  }
  __syncthreads();
  const float Cb = CbSh;
  float4* ob = (float4*)(out + (g << 14));
#pragma unroll
  for (int j = 0; j < 4; ++j) {
    int e4 = tid + (j << 10);             // float4 index 0..4095
    float a = Ash[e4 >> 5] + Cb;
    float4 bv = ((const float4*)Bsh)[e4 & 31];
    float4 r;
    r.x = 1.f / (1.f + __expf(-(a + bv.x)));
    r.y = 1.f / (1.f + __expf(-(a + bv.y)));
    r.z = 1.f / (1.f + __expf(-(a + bv.z)));
    r.w = 1.f / (1.f + __expf(-(a + bv.w)));
    ob[e4] = r;
  }
}

extern "C" void kernel_launch(void* const* d_in, const int* in_sizes, int n_in,
                              void* d_out, int out_size, void* d_ws, size_t ws_size,
                              hipStream_t stream) {
  const float* Xs  = (const float*)d_in[0];
  const float* api = (const float*)d_in[1];
  const float* W1  = (const float*)d_in[2];
  const float* b1  = (const float*)d_in[3];
  const float* W2  = (const float*)d_in[4];
  const float* b2  = (const float*)d_in[5];
  const float* W3  = (const float*)d_in[6];
  const float* b3  = (const float*)d_in[7];
  const float* W4  = (const float*)d_in[8];
  const float* b4  = (const float*)d_in[9];
  const int* invoked = (const int*)d_in[10];
  float* out = (float*)d_out;
  float* ws = (float*)d_ws;

  hipLaunchKernelGGL(k1, dim3(257), dim3(256), 0, stream,
                     Xs, W1, b1, W2, b2, W3, b3, W4, b4, ws);
  hipLaunchKernelGGL(k2, dim3(129), dim3(256), 0, stream, ws);
  hipLaunchKernelGGL(k3, dim3(8), dim3(1024), 0, stream,
                     api, invoked, ws, out);
}

// Round 6
// 25.978 us; speedup vs baseline: 3.3160x; 1.1242x over previous
//
#include <hip/hip_runtime.h>

// AdaptiveHyperNN, collapsed + matmul-flattened to dependency depth 2:
//   logit[b,u,v] = feat_u·va + feat_v·vb + Cb, sigmoid at the end.
//   Node 1 (all independent): PM GEMM (W1@W2bot + W2top), wa/wb = W3@w4t,
//     c0 scalars, PM[512] = W2bot^T@b1 + b2, gather feat -> ws.
//   Node 2: va/vb = PM[256:]·w{a,b}; qsum = PM[:256]·(wa+wb); cAll.
//   Node 3 (per graph): A/B/sc dots from staged feat, Cb, sigmoid.
// R3 lesson: cross-block atomics cost 15-20 µs/round — never. R4 lesson:
// <16 CUs streaming = 24 GB/s/CU — keep every stage wide. R5 lesson:
// 256-deep serial k-loops at 1 block/CU dominate — split k across waves.

__device__ __forceinline__ float wred(float v) {
#pragma unroll
  for (int o = 32; o > 0; o >>= 1) v += __shfl_xor(v, o, 64);
  return v;
}
__device__ __forceinline__ float dot4(float4 a, float4 b) {
  return a.x * b.x + a.y * b.y + a.z * b.z + a.w * b.w;
}

// ws float offsets
#define OFF_PM   0        // 513*256 = 131328
#define OFF_WA   131328   // 256
#define OFF_WB   131584   // 256
#define OFF_VA   131840   // 256
#define OFF_VB   132096   // 256
#define OFF_QS   132352   // 256
#define OFF_C0   132608   // 8
#define OFF_CALL 132616   // 8
#define OFF_FEAT 132624   // 1024*256 = 262144 (16B-aligned: 132624*4 % 16 == 0)
#define WS_FLOATS_STAGED (OFF_FEAT + 262144)

// Node 1. blocks 0..255: PM GEMM, 2 rows/block, k split over 4 waves;
// blocks 256..383: wa/wb wave-per-row; block 384: c0 + PM[512];
// blocks 385..640 (staged only): gather feat.
__global__ __launch_bounds__(256) void k1(
    const float* __restrict__ Xs, const float* __restrict__ api,
    const float* __restrict__ W1, const float* __restrict__ b1,
    const float* __restrict__ W2, const float* __restrict__ b2,
    const float* __restrict__ W3, const float* __restrict__ b3,
    const float* __restrict__ W4, const float* __restrict__ b4,
    const int* __restrict__ invoked, float* __restrict__ ws) {
  const int blk = blockIdx.x, tid = threadIdx.x;
  float* PM = ws + OFF_PM;
  const float* W2bot = W2 + 256 * 256;
  __shared__ float w1s[2][256];
  __shared__ float4 part[2][4][64];

  if (blk < 256) {
    // ---- PM rows 2b, 2b+1 ----
    const int r0 = blk * 2;
    const int c4 = tid & 63, wv = tid >> 6;
    ((float*)w1s)[tid]       = W1[(size_t)r0 * 256 + tid];
    ((float*)w1s)[tid + 256] = W1[(size_t)r0 * 256 + 256 + tid];
    __syncthreads();
    const float4* w2b4 = (const float4*)W2bot;
    float4 a0 = make_float4(0.f, 0.f, 0.f, 0.f);
    float4 a1 = make_float4(0.f, 0.f, 0.f, 0.f);
    const int kb = wv * 64;
#pragma unroll 8
    for (int i = 0; i < 64; ++i) {
      int k = kb + i;
      float4 w = w2b4[k * 64 + c4];
      float x0 = w1s[0][k], x1 = w1s[1][k];
      a0.x += x0 * w.x; a0.y += x0 * w.y; a0.z += x0 * w.z; a0.w += x0 * w.w;
      a1.x += x1 * w.x; a1.y += x1 * w.y; a1.z += x1 * w.z; a1.w += x1 * w.w;
    }
    part[0][wv][c4] = a0;
    part[1][wv][c4] = a1;
    __syncthreads();
    if (tid < 128) {
      int row = tid >> 6, c = tid & 63;
      float4 p0 = part[row][0][c], p1 = part[row][1][c];
      float4 p2 = part[row][2][c], p3 = part[row][3][c];
      float4 s = make_float4(p0.x + p1.x + p2.x + p3.x,
                             p0.y + p1.y + p2.y + p3.y,
                             p0.z + p1.z + p2.z + p3.z,
                             p0.w + p1.w + p2.w + p3.w);
      int r = r0 + row;
      if (r >= 256) {
        float4 t = ((const float4*)(W2 + (size_t)(r - 256) * 256))[c];
        s.x += t.x; s.y += t.y; s.z += t.z; s.w += t.w;
      }
      ((float4*)(PM + (size_t)r * 256))[c] = s;
    }
  } else if (blk < 384) {
    // ---- wa/wb = W3 @ w4t, wave per row ----
    const int lane = tid & 63, wv = tid >> 6;
    const int t = (blk - 256) * 4 + wv;  // 0..511
    float4 w4a = ((const float4*)W4)[lane];
    float4 rv = ((const float4*)(W3 + (size_t)t * 256))[lane];
    float s = wred(dot4(rv, w4a));
    if (lane == 0) {
      if (t < 256) ws[OFF_WA + t] = s; else ws[OFF_WB + t - 256] = s;
    }
  } else if (blk == 384) {
    // ---- c0 scalars + PM[512] = W2bot^T @ b1 + b2 ----
    const int lane = tid & 63, wv = tid >> 6;
    float4 w4a = ((const float4*)W4)[lane];
    float4 w4b4 = ((const float4*)W4)[lane + 64];
    float sb3 = wred(dot4(((const float4*)b3)[lane], w4a));
    for (int bi = wv; bi < 8; bi += 4) {
      float xd = wred(dot4(((const float4*)(Xs + (size_t)bi * 256))[lane], w4b4));
      if (lane == 0) ws[OFF_C0 + bi] = b4[0] + sb3 + xd;
    }
    const int c4 = tid & 63, rg = tid >> 6;
    const float4* w2b4 = (const float4*)W2bot;
    float4 acc = make_float4(0.f, 0.f, 0.f, 0.f);
#pragma unroll 8
    for (int i = 0; i < 64; ++i) {
      int k = rg * 64 + i;
      float4 w = w2b4[k * 64 + c4];
      float bv = b1[k];
      acc.x += bv * w.x; acc.y += bv * w.y; acc.z += bv * w.z; acc.w += bv * w.w;
    }
    part[0][rg][c4] = acc;
    __syncthreads();
    if (tid < 64) {
      float4 p0 = part[0][0][tid], p1 = part[0][1][tid];
      float4 p2 = part[0][2][tid], p3 = part[0][3][tid];
      float4 bb = ((const float4*)b2)[tid];
      float4 s = make_float4(p0.x + p1.x + p2.x + p3.x + bb.x,
                             p0.y + p1.y + p2.y + p3.y + bb.y,
                             p0.z + p1.z + p2.z + p3.z + bb.z,
                             p0.w + p1.w + p2.w + p3.w + bb.w);
      ((float4*)(PM + (size_t)512 * 256))[tid] = s;
    }
  } else {
    // ---- gather feat -> ws (staged mode only) ----
    const int lane = tid & 63, wv = tid >> 6;
    const int row = (blk - 385) * 4 + wv;  // 0..1023
    int idx = invoked[row];                // wave-uniform
    ((float4*)(ws + OFF_FEAT + (size_t)row * 256))[lane] =
        ((const float4*)(api + (size_t)idx * 256))[lane];
  }
}

// Node 2: blocks 0..127 wave-per-row dots against PM; block 128: cAll.
__global__ __launch_bounds__(256) void k2(float* __restrict__ ws) {
  const int blk = blockIdx.x, tid = threadIdx.x;
  const int lane = tid & 63, wv = tid >> 6;
  const float* PM = ws + OFF_PM;
  float4 wa4 = ((const float4*)(ws + OFF_WA))[lane];
  float4 wb4 = ((const float4*)(ws + OFF_WB))[lane];
  if (blk < 128) {
    const int t = blk * 4 + wv;  // 0..511, wave-uniform branch
    if (t < 256) {
      float4 rv = ((const float4*)(PM + (size_t)(256 + t) * 256))[lane];
      float sa = wred(dot4(rv, wa4));
      float sb = wred(dot4(rv, wb4));
      if (lane == 0) { ws[OFF_VA + t] = sa; ws[OFF_VB + t] = sb; }
    } else {
      float4 rv = ((const float4*)(PM + (size_t)(t - 256) * 256))[lane];
      float4 s4 = make_float4(wa4.x + wb4.x, wa4.y + wb4.y,
                              wa4.z + wb4.z, wa4.w + wb4.w);
      float s = wred(dot4(rv, s4));
      if (lane == 0) ws[OFF_QS + t - 256] = s;
    }
  } else {
    __shared__ float sAllSh;
    if (wv == 0) {
      float4 rv = ((const float4*)(PM + (size_t)512 * 256))[lane];
      float4 s4 = make_float4(wa4.x + wb4.x, wa4.y + wb4.y,
                              wa4.z + wb4.z, wa4.w + wb4.w);
      float s = wred(dot4(rv, s4));
      if (lane == 0) sAllSh = s;
    }
    __syncthreads();
    if (tid < 8) ws[OFF_CALL + tid] = ws[OFF_C0 + tid] + sAllSh;
  }
}

// Node 3: one block (1024 thr) per graph. staged: feat streamed from ws;
// else gathered from api. Then 3 dots/row, Cb, sigmoid.
__global__ __launch_bounds__(1024) void k3(
    const float* __restrict__ api, const int* __restrict__ invoked,
    const float* __restrict__ ws, float* __restrict__ out, int staged) {
  const int g = blockIdx.x, tid = threadIdx.x;
  const int lane = tid & 63, wv = tid >> 6;  // wv 0..15
  __shared__ float Ash[128], Bsh[128], scsh[128];
  __shared__ float CbSh;

  float4 f[8];
  const int ub = wv * 8;
  if (staged) {
    const float4* fp =
        (const float4*)(ws + OFF_FEAT + (size_t)((g << 7) + ub) * 256);
#pragma unroll
    for (int i = 0; i < 8; ++i) f[i] = fp[(size_t)i * 64 + lane];
  } else {
    int idx[8];
#pragma unroll
    for (int i = 0; i < 8; ++i) idx[i] = invoked[(g << 7) + ub + i];
#pragma unroll
    for (int i = 0; i < 8; ++i)
      f[i] = ((const float4*)(api + (size_t)idx[i] * 256))[lane];
  }

  float4 va4 = ((const float4*)(ws + OFF_VA))[lane];
  float4 vb4 = ((const float4*)(ws + OFF_VB))[lane];
  float4 q4  = ((const float4*)(ws + OFF_QS))[lane];
#pragma unroll
  for (int i = 0; i < 8; ++i) {
    float sa = wred(dot4(f[i], va4));
    float sb = wred(dot4(f[i], vb4));
    float sc = wred(dot4(f[i], q4));
    if (lane == 0) { Ash[ub + i] = sa; Bsh[ub + i] = sb; scsh[ub + i] = sc; }
  }
  __syncthreads();
  if (wv == 0) {  // deterministic fixed-order Cb reduction
    float t = scsh[lane] + scsh[lane + 64];
    t = wred(t);
    if (lane == 0) CbSh = t * (1.f / 128.f) + ws[OFF_CALL + g];
  }
  __syncthreads();
  const float Cb = CbSh;
  float4* ob = (float4*)(out + (g << 14));
#pragma unroll
  for (int j = 0; j < 4; ++j) {
    int e4 = tid + (j << 10);  // float4 index 0..4095
    float a = Ash[e4 >> 5] + Cb;
    float4 bv = ((const float4*)Bsh)[e4 & 31];
    float4 r;
    r.x = 1.f / (1.f + __expf(-(a + bv.x)));
    r.y = 1.f / (1.f + __expf(-(a + bv.y)));
    r.z = 1.f / (1.f + __expf(-(a + bv.z)));
    r.w = 1.f / (1.f + __expf(-(a + bv.w)));
    ob[e4] = r;
  }
}

extern "C" void kernel_launch(void* const* d_in, const int* in_sizes, int n_in,
                              void* d_out, int out_size, void* d_ws, size_t ws_size,
                              hipStream_t stream) {
  const float* Xs  = (const float*)d_in[0];
  const float* api = (const float*)d_in[1];
  const float* W1  = (const float*)d_in[2];
  const float* b1  = (const float*)d_in[3];
  const float* W2  = (const float*)d_in[4];
  const float* b2  = (const float*)d_in[5];
  const float* W3  = (const float*)d_in[6];
  const float* b3  = (const float*)d_in[7];
  const float* W4  = (const float*)d_in[8];
  const float* b4  = (const float*)d_in[9];
  const int* invoked = (const int*)d_in[10];
  float* out = (float*)d_out;
  float* ws = (float*)d_ws;

  const int staged = (ws_size >= (size_t)WS_FLOATS_STAGED * sizeof(float));
  hipLaunchKernelGGL(k1, dim3(staged ? 641 : 385), dim3(256), 0, stream,
                     Xs, api, W1, b1, W2, b2, W3, b3, W4, b4, invoked, ws);
  hipLaunchKernelGGL(k2, dim3(129), dim3(256), 0, stream, ws);
  hipLaunchKernelGGL(k3, dim3(8), dim3(1024), 0, stream,
                     api, invoked, ws, out, staged);
}

// Round 7
// 22.970 us; speedup vs baseline: 3.7503x; 1.1310x over previous
//
#include <hip/hip_runtime.h>

// AdaptiveHyperNN, collapsed + matmul-flattened to dependency depth 2:
//   logit[b,u,v] = feat_u·va + feat_v·vb + Cb, sigmoid at the end.
//   Node 1 (independent): PM GEMM (PM[0:256]=W1top@W2bot; PM[256:512]=
//     W2top+W1bot@W2bot; PM[512]=W2bot^T@b1+b2), wa/wb = W3@w4t, c0.
//   Node 2: va/vb = PM[256:]·w{a,b}; qsum = PM[:256]·(wa+wb); cAll.
//   Node 3: per graph (8 blocks each): gather feat from L3-resident api,
//     A/B/sc dots (redundant per block, identical order), Cb, sigmoid slice.
// Lessons: R3 cross-block atomics 15-20 µs/round — never. R4: <16 CUs
// streaming = latency-bound. R5: deep serial k-loops — split k over waves.
// R6: per-block W2bot stream is fixed 256 KB — use fewer, fatter blocks.

__device__ __forceinline__ float wred(float v) {
#pragma unroll
  for (int o = 32; o > 0; o >>= 1) v += __shfl_xor(v, o, 64);
  return v;
}
__device__ __forceinline__ float dot4(float4 a, float4 b) {
  return a.x * b.x + a.y * b.y + a.z * b.z + a.w * b.w;
}

// ws float offsets
#define OFF_PM   0        // 513*256 = 131328
#define OFF_WA   131328   // 256
#define OFF_WB   131584   // 256
#define OFF_VA   131840   // 256
#define OFF_VB   132096   // 256
#define OFF_QS   132352   // 256
#define OFF_C0   132608   // 8
#define OFF_CALL 132616   // 8   (total ~530 KB)

// Node 1. blocks 0..63: PM GEMM, 8 rows/block, k split over 4 waves;
// blocks 64..191: wa/wb wave-per-row; block 192: c0 + PM[512].
__global__ __launch_bounds__(256) void k1(
    const float* __restrict__ Xs,
    const float* __restrict__ W1, const float* __restrict__ b1,
    const float* __restrict__ W2, const float* __restrict__ b2,
    const float* __restrict__ W3, const float* __restrict__ b3,
    const float* __restrict__ W4, const float* __restrict__ b4,
    float* __restrict__ ws) {
  const int blk = blockIdx.x, tid = threadIdx.x;
  float* PM = ws + OFF_PM;
  const float* W2bot = W2 + 256 * 256;
  __shared__ float w1s[8][256];
  __shared__ float4 part[8][4][64];

  if (blk < 64) {
    // ---- PM rows r0..r0+7 ----
    const int r0 = blk * 8;
    const int c4 = tid & 63, wv = tid >> 6;
#pragma unroll
    for (int i = 0; i < 8; ++i)
      ((float*)w1s)[i * 256 + tid] = W1[(size_t)r0 * 256 + i * 256 + tid];
    __syncthreads();
    const float4* w2b4 = (const float4*)W2bot;
    float4 acc[8];
#pragma unroll
    for (int i = 0; i < 8; ++i) acc[i] = make_float4(0.f, 0.f, 0.f, 0.f);
    const int kb = wv * 64;
#pragma unroll 4
    for (int i = 0; i < 64; ++i) {
      int k = kb + i;
      float4 w = w2b4[k * 64 + c4];
#pragma unroll
      for (int r = 0; r < 8; ++r) {
        float x = w1s[r][k];
        acc[r].x += x * w.x; acc[r].y += x * w.y;
        acc[r].z += x * w.z; acc[r].w += x * w.w;
      }
    }
#pragma unroll
    for (int r = 0; r < 8; ++r) part[r][wv][c4] = acc[r];
    __syncthreads();
    // 512 outputs (row,c4) over 256 threads, 2 each; fixed order 0+1+2+3
#pragma unroll
    for (int j = 0; j < 2; ++j) {
      int item = tid + j * 256;
      int row = item >> 6, c = item & 63;
      float4 p0 = part[row][0][c], p1 = part[row][1][c];
      float4 p2 = part[row][2][c], p3 = part[row][3][c];
      float4 s = make_float4(p0.x + p1.x + p2.x + p3.x,
                             p0.y + p1.y + p2.y + p3.y,
                             p0.z + p1.z + p2.z + p3.z,
                             p0.w + p1.w + p2.w + p3.w);
      int r = r0 + row;
      if (r >= 256) {
        float4 t = ((const float4*)(W2 + (size_t)(r - 256) * 256))[c];
        s.x += t.x; s.y += t.y; s.z += t.z; s.w += t.w;
      }
      ((float4*)(PM + (size_t)r * 256))[c] = s;
    }
  } else if (blk < 192) {
    // ---- wa/wb = W3 @ w4t, wave per row ----
    const int lane = tid & 63, wv = tid >> 6;
    const int t = (blk - 64) * 4 + wv;  // 0..511
    float4 w4a = ((const float4*)W4)[lane];
    float4 rv = ((const float4*)(W3 + (size_t)t * 256))[lane];
    float s = wred(dot4(rv, w4a));
    if (lane == 0) {
      if (t < 256) ws[OFF_WA + t] = s; else ws[OFF_WB + t - 256] = s;
    }
  } else {
    // ---- c0 scalars + PM[512] = W2bot^T @ b1 + b2 ----
    const int lane = tid & 63, wv = tid >> 6;
    float4 w4a = ((const float4*)W4)[lane];
    float4 w4b4 = ((const float4*)W4)[lane + 64];
    float sb3 = wred(dot4(((const float4*)b3)[lane], w4a));
    for (int bi = wv; bi < 8; bi += 4) {
      float xd = wred(dot4(((const float4*)(Xs + (size_t)bi * 256))[lane], w4b4));
      if (lane == 0) ws[OFF_C0 + bi] = b4[0] + sb3 + xd;
    }
    const int c4 = tid & 63, rg = tid >> 6;
    const float4* w2b4 = (const float4*)W2bot;
    float4 acc = make_float4(0.f, 0.f, 0.f, 0.f);
#pragma unroll 8
    for (int i = 0; i < 64; ++i) {
      int k = rg * 64 + i;
      float4 w = w2b4[k * 64 + c4];
      float bv = b1[k];
      acc.x += bv * w.x; acc.y += bv * w.y; acc.z += bv * w.z; acc.w += bv * w.w;
    }
    part[0][rg][c4] = acc;
    __syncthreads();
    if (tid < 64) {
      float4 p0 = part[0][0][tid], p1 = part[0][1][tid];
      float4 p2 = part[0][2][tid], p3 = part[0][3][tid];
      float4 bb = ((const float4*)b2)[tid];
      float4 s = make_float4(p0.x + p1.x + p2.x + p3.x + bb.x,
                             p0.y + p1.y + p2.y + p3.y + bb.y,
                             p0.z + p1.z + p2.z + p3.z + bb.z,
                             p0.w + p1.w + p2.w + p3.w + bb.w);
      ((float4*)(PM + (size_t)512 * 256))[tid] = s;
    }
  }
}

// Node 2: blocks 0..127 wave-per-row dots against PM; block 128: cAll.
__global__ __launch_bounds__(256) void k2(float* __restrict__ ws) {
  const int blk = blockIdx.x, tid = threadIdx.x;
  const int lane = tid & 63, wv = tid >> 6;
  const float* PM = ws + OFF_PM;
  float4 wa4 = ((const float4*)(ws + OFF_WA))[lane];
  float4 wb4 = ((const float4*)(ws + OFF_WB))[lane];
  if (blk < 128) {
    const int t = blk * 4 + wv;  // 0..511, wave-uniform branch
    if (t < 256) {
      float4 rv = ((const float4*)(PM + (size_t)(256 + t) * 256))[lane];
      float sa = wred(dot4(rv, wa4));
      float sb = wred(dot4(rv, wb4));
      if (lane == 0) { ws[OFF_VA + t] = sa; ws[OFF_VB + t] = sb; }
    } else {
      float4 rv = ((const float4*)(PM + (size_t)(t - 256) * 256))[lane];
      float4 s4 = make_float4(wa4.x + wb4.x, wa4.y + wb4.y,
                              wa4.z + wb4.z, wa4.w + wb4.w);
      float s = wred(dot4(rv, s4));
      if (lane == 0) ws[OFF_QS + t - 256] = s;
    }
  } else {
    __shared__ float sAllSh;
    if (wv == 0) {
      float4 rv = ((const float4*)(PM + (size_t)512 * 256))[lane];
      float4 s4 = make_float4(wa4.x + wb4.x, wa4.y + wb4.y,
                              wa4.z + wb4.z, wa4.w + wb4.w);
      float s = wred(dot4(rv, s4));
      if (lane == 0) sAllSh = s;
    }
    __syncthreads();
    if (tid < 8) ws[OFF_CALL + tid] = ws[OFF_C0 + tid] + sAllSh;
  }
}

// Node 3: 8 blocks per graph (64 total), 1024 threads. Each block gathers
// its graph's 128 feat rows (api is L3-resident), computes the full
// A/B/sc dot set (identical order in every block -> identical values),
// then writes its 16-row output slice.
__global__ __launch_bounds__(1024) void k3(
    const float* __restrict__ api, const int* __restrict__ invoked,
    const float* __restrict__ ws, float* __restrict__ out) {
  const int g = blockIdx.x >> 3, sub = blockIdx.x & 7;
  const int tid = threadIdx.x;
  const int lane = tid & 63, wv = tid >> 6;  // wv 0..15
  __shared__ alignas(16) float Ash[128], Bsh[128], scsh[128];
  __shared__ float CbSh;

  // gather 8 rows/wave into regs
  float4 f[8];
  const int ub = wv * 8;
  int idx[8];
#pragma unroll
  for (int i = 0; i < 8; ++i) idx[i] = invoked[(g << 7) + ub + i];
#pragma unroll
  for (int i = 0; i < 8; ++i)
    f[i] = ((const float4*)(api + (size_t)idx[i] * 256))[lane];

  float4 va4 = ((const float4*)(ws + OFF_VA))[lane];
  float4 vb4 = ((const float4*)(ws + OFF_VB))[lane];
  float4 q4  = ((const float4*)(ws + OFF_QS))[lane];
#pragma unroll
  for (int i = 0; i < 8; ++i) {
    float sa = wred(dot4(f[i], va4));
    float sb = wred(dot4(f[i], vb4));
    float sc = wred(dot4(f[i], q4));
    if (lane == 0) { Ash[ub + i] = sa; Bsh[ub + i] = sb; scsh[ub + i] = sc; }
  }
  __syncthreads();
  if (wv == 0) {  // deterministic fixed-order Cb reduction
    float t = scsh[lane] + scsh[lane + 64];
    t = wred(t);
    if (lane == 0) CbSh = t * (1.f / 128.f) + ws[OFF_CALL + g];
  }
  __syncthreads();
  const float Cb = CbSh;
  // this block's slice: u in [sub*16, sub*16+16) -> 16*128 = 512 float4
  if (tid < 512) {
    int u = (sub << 4) + (tid >> 5);   // 32 float4 per row
    int v4 = tid & 31;
    float a = Ash[u] + Cb;
    float4 bv = ((const float4*)Bsh)[v4];
    float4 r;
    r.x = 1.f / (1.f + __expf(-(a + bv.x)));
    r.y = 1.f / (1.f + __expf(-(a + bv.y)));
    r.z = 1.f / (1.f + __expf(-(a + bv.z)));
    r.w = 1.f / (1.f + __expf(-(a + bv.w)));
    ((float4*)(out + (g << 14) + (u << 7)))[v4] = r;
  }
}

extern "C" void kernel_launch(void* const* d_in, const int* in_sizes, int n_in,
                              void* d_out, int out_size, void* d_ws, size_t ws_size,
                              hipStream_t stream) {
  const float* Xs  = (const float*)d_in[0];
  const float* api = (const float*)d_in[1];
  const float* W1  = (const float*)d_in[2];
  const float* b1  = (const float*)d_in[3];
  const float* W2  = (const float*)d_in[4];
  const float* b2  = (const float*)d_in[5];
  const float* W3  = (const float*)d_in[6];
  const float* b3  = (const float*)d_in[7];
  const float* W4  = (const float*)d_in[8];
  const float* b4  = (const float*)d_in[9];
  const int* invoked = (const int*)d_in[10];
  float* out = (float*)d_out;
  float* ws = (float*)d_ws;

  hipLaunchKernelGGL(k1, dim3(193), dim3(256), 0, stream,
                     Xs, W1, b1, W2, b2, W3, b3, W4, b4, ws);
  hipLaunchKernelGGL(k2, dim3(129), dim3(256), 0, stream, ws);
  hipLaunchKernelGGL(k3, dim3(64), dim3(1024), 0, stream,
                     api, invoked, ws, out);
}